// Round 1
// baseline (1633.137 us; speedup 1.0000x reference)
//
#include <hip/hip_runtime.h>
#include <math.h>
#include <stdint.h>

#define B_   4
#define S_   2048
#define DM_  1024
#define H_   16
#define DK_  64

typedef __bf16 bhalf;
typedef __bf16 bhalf8 __attribute__((ext_vector_type(8)));
typedef float  f32x4  __attribute__((ext_vector_type(4)));

typedef const __attribute__((address_space(1))) void g_void;
typedef __attribute__((address_space(3))) void l_void;

// async global->LDS, 16B per lane. LDS dest must be wave-uniform base + lane*16.
__device__ __forceinline__ void gld16(const void* g, void* l) {
  __builtin_amdgcn_global_load_lds((g_void*)g, (l_void*)l, 16, 0, 0);
}

// ---------------- fp32 -> bf16 convert, 8 elems/thread ----------------
__global__ __launch_bounds__(256) void cvt_kernel(const float* __restrict__ src,
                                                  bhalf* __restrict__ dst, int n) {
  int i = (blockIdx.x * 256 + threadIdx.x) * 8;
  if (i >= n) return;
  float4 a = *(const float4*)(src + i);
  float4 b = *(const float4*)(src + i + 4);
  bhalf8 o;
  o[0] = (bhalf)a.x; o[1] = (bhalf)a.y; o[2] = (bhalf)a.z; o[3] = (bhalf)a.w;
  o[4] = (bhalf)b.x; o[5] = (bhalf)b.y; o[6] = (bhalf)b.z; o[7] = (bhalf)b.w;
  *(bhalf8*)(dst + i) = o;
}

// ---------------- mask int32 -> bit-packed u64 words ----------------
__global__ __launch_bounds__(256) void maskpack_kernel(const int* __restrict__ mask,
                                                       unsigned long long* __restrict__ out) {
  int i = blockIdx.x * 256 + threadIdx.x;   // over B*S*S
  unsigned long long bits = __ballot(mask[i] != 0);
  if ((threadIdx.x & 63) == 0) out[i >> 6] = bits;
}

// ---------------- bf16 GEMM  C[M=8192, N=1024] = A * B^T  (K=1024) ----------------
// MODE 0: head-split write  dst16[((b*H+h)*S + s)*DK + d] = acc*scale   (Qh/Kh)
// MODE 1: transposed head-split dst16[((b*H+h)*DK + d)*S + s] = acc      (Vt)
// MODE 2: fp32 write d32[m*1024+n] = acc + bias[n]                       (out proj)
template <int MODE>
__global__ __launch_bounds__(256) void gemm_bt(const bhalf* __restrict__ A,
                                               const bhalf* __restrict__ Bm,
                                               bhalf* __restrict__ d16,
                                               float* __restrict__ d32,
                                               const float* __restrict__ bias,
                                               float scale) {
  constexpr int K = 1024;
  __shared__ __align__(16) bhalf As[128 * 64];
  __shared__ __align__(16) bhalf Bs[128 * 64];
  const int tid = threadIdx.x;
  const int lane = tid & 63;
  const int w = tid >> 6;
  const int wm = w & 1, wn = w >> 1;
  const int bm = blockIdx.y, bn = blockIdx.x;
  const bhalf* Ab = A + (long)bm * 128 * K;
  const bhalf* Bb = Bm + (long)bn * 128 * K;
  const int l15 = lane & 15, l4 = lane >> 4;
  f32x4 acc[4][4] = {};
  for (int kt = 0; kt < K / 64; ++kt) {
#pragma unroll
    for (int j = 0; j < 4; ++j) {
      int c = j * 256 + tid;                 // 1024 chunks of 16B per tile
      int r = c >> 3, ko = (c & 7) * 8;
      gld16(Ab + (long)r * K + kt * 64 + ko, &As[c * 8]);
      gld16(Bb + (long)r * K + kt * 64 + ko, &Bs[c * 8]);
    }
    __syncthreads();
#pragma unroll
    for (int t = 0; t < 2; ++t) {
      bhalf8 af[4], bfr[4];
#pragma unroll
      for (int i = 0; i < 4; ++i)
        af[i] = *(const bhalf8*)&As[(wm * 64 + i * 16 + l15) * 64 + t * 32 + l4 * 8];
#pragma unroll
      for (int j = 0; j < 4; ++j)
        bfr[j] = *(const bhalf8*)&Bs[(wn * 64 + j * 16 + l15) * 64 + t * 32 + l4 * 8];
#pragma unroll
      for (int i = 0; i < 4; ++i)
#pragma unroll
        for (int j = 0; j < 4; ++j)
          acc[i][j] = __builtin_amdgcn_mfma_f32_16x16x32_bf16(af[i], bfr[j], acc[i][j], 0, 0, 0);
    }
    __syncthreads();
  }
  // epilogue: C layout col = lane&15, row = (lane>>4)*4 + r
#pragma unroll
  for (int i = 0; i < 4; ++i) {
#pragma unroll
    for (int j = 0; j < 4; ++j) {
#pragma unroll
      for (int r = 0; r < 4; ++r) {
        int gm = bm * 128 + wm * 64 + i * 16 + l4 * 4 + r;
        int gn = bn * 128 + wn * 64 + j * 16 + l15;
        float v = acc[i][j][r];
        if (MODE == 0) {
          int b = gm >> 11, s = gm & 2047, h = gn >> 6, d = gn & 63;
          d16[((long)(b * H_ + h) * S_ + s) * DK_ + d] = (bhalf)(v * scale);
        } else if (MODE == 1) {
          int b = gm >> 11, s = gm & 2047, h = gn >> 6, d = gn & 63;
          d16[((long)(b * H_ + h) * DK_ + d) * S_ + s] = (bhalf)v;
        } else {
          d32[(long)gm * 1024 + gn] = v + bias[gn];
        }
      }
    }
  }
}

// ---------------- fused attention: scores+mask+softmax+P-write+PV ----------------
// grid: B*H*16 workgroups; each handles (b,h, 128-row q tile), two passes over K.
__global__ __launch_bounds__(256, 2) void attn_kernel(const bhalf* __restrict__ Qh,
                                                      const bhalf* __restrict__ Kh,
                                                      const bhalf* __restrict__ Vt,
                                                      const unsigned long long* __restrict__ mb,
                                                      bhalf* __restrict__ ctx,
                                                      float* __restrict__ att) {
  __shared__ __align__(16) bhalf Qs[128 * 64];    // 16 KB, resident
  __shared__ __align__(16) bhalf Ps[128 * 128];   // 32 KB; first 16 KB doubles as K tile
  __shared__ __align__(16) bhalf Vs[64 * 128];    // 16 KB, Vs[d][s_local]
  __shared__ float rsum[128];
  __shared__ float rinv[128];
  bhalf* Ks = Ps;

  const int tid = threadIdx.x, lane = tid & 63, w = tid >> 6;
  const int wm = w & 1, wn = w >> 1;
  const int l15 = lane & 15, l4 = lane >> 4;
  const int bid = blockIdx.x;
  const int qt = bid & 15;
  const int bh = bid >> 4;        // b*16 + h
  const int b = bh >> 4;
  const long qkBase = (long)bh * S_ * DK_;
  const bhalf* Qg = Qh + qkBase + (long)qt * 128 * DK_;

  if (tid < 128) rsum[tid] = 0.f;
#pragma unroll
  for (int j = 0; j < 4; ++j) { int c = j * 256 + tid; gld16(Qg + c * 8, &Qs[c * 8]); }
  __syncthreads();

  const int lrow0 = wm * 64 + l4 * 4;   // + i*16 + r  -> local q row
  const int colin = wn * 64 + l15;      // + jn*16     -> local k col

  // -------- pass 1: row sums of exp(s) --------
  float psum[4][4] = {};
  for (int kt = 0; kt < 16; ++kt) {
    const bhalf* Kg = Kh + qkBase + (long)kt * 128 * DK_;
#pragma unroll
    for (int j = 0; j < 4; ++j) { int c = j * 256 + tid; gld16(Kg + c * 8, &Ks[c * 8]); }
    __syncthreads();
#pragma unroll
    for (int i = 0; i < 4; ++i) {
      bhalf8 aq0 = *(const bhalf8*)&Qs[(wm * 64 + i * 16 + l15) * 64 + l4 * 8];
      bhalf8 aq1 = *(const bhalf8*)&Qs[(wm * 64 + i * 16 + l15) * 64 + 32 + l4 * 8];
      unsigned long long mword[4];
#pragma unroll
      for (int r = 0; r < 4; ++r)
        mword[r] = mb[((long)b * S_ + qt * 128 + lrow0 + i * 16 + r) * 32 + kt * 2 + wn];
#pragma unroll
      for (int jn = 0; jn < 4; ++jn) {
        bhalf8 bk0 = *(const bhalf8*)&Ks[(wn * 64 + jn * 16 + l15) * 64 + l4 * 8];
        bhalf8 bk1 = *(const bhalf8*)&Ks[(wn * 64 + jn * 16 + l15) * 64 + 32 + l4 * 8];
        f32x4 sacc = {};
        sacc = __builtin_amdgcn_mfma_f32_16x16x32_bf16(aq0, bk0, sacc, 0, 0, 0);
        sacc = __builtin_amdgcn_mfma_f32_16x16x32_bf16(aq1, bk1, sacc, 0, 0, 0);
        int bit = jn * 16 + l15;
#pragma unroll
        for (int r = 0; r < 4; ++r)
          psum[i][r] += ((mword[r] >> bit) & 1ull) ? __expf(sacc[r]) : 0.f;
      }
    }
    __syncthreads();
  }
  // reduce across the 16 lanes holding one row's columns
#pragma unroll
  for (int i = 0; i < 4; ++i)
#pragma unroll
    for (int r = 0; r < 4; ++r) {
      float v = psum[i][r];
      v += __shfl_xor(v, 1); v += __shfl_xor(v, 2);
      v += __shfl_xor(v, 4); v += __shfl_xor(v, 8);
      if (l15 == 0) atomicAdd(&rsum[lrow0 + i * 16 + r], v);
    }
  __syncthreads();
  if (tid < 128) rinv[tid] = 1.f / rsum[tid];
  __syncthreads();

  // -------- pass 2: recompute, normalize, write P, PV --------
  f32x4 oacc[2][4] = {};
  const int prow = w * 32;   // PV: wave w handles q rows [prow, prow+32)
  for (int kt = 0; kt < 16; ++kt) {
    const bhalf* Kg = Kh + qkBase + (long)kt * 128 * DK_;
    const bhalf* Vg = Vt + qkBase + kt * 128;   // Vt: [bh][64][2048]
#pragma unroll
    for (int j = 0; j < 4; ++j) { int c = j * 256 + tid; gld16(Kg + c * 8, &Ks[c * 8]); }
#pragma unroll
    for (int j = 0; j < 4; ++j) {
      int c = j * 256 + tid;
      int d = c >> 4, so = (c & 15) * 8;
      gld16(Vg + (long)d * S_ + so, &Vs[d * 128 + so]);
    }
    __syncthreads();
    float pv[4][4][4];
#pragma unroll
    for (int i = 0; i < 4; ++i) {
      bhalf8 aq0 = *(const bhalf8*)&Qs[(wm * 64 + i * 16 + l15) * 64 + l4 * 8];
      bhalf8 aq1 = *(const bhalf8*)&Qs[(wm * 64 + i * 16 + l15) * 64 + 32 + l4 * 8];
      unsigned long long mword[4];
#pragma unroll
      for (int r = 0; r < 4; ++r)
        mword[r] = mb[((long)b * S_ + qt * 128 + lrow0 + i * 16 + r) * 32 + kt * 2 + wn];
#pragma unroll
      for (int jn = 0; jn < 4; ++jn) {
        bhalf8 bk0 = *(const bhalf8*)&Ks[(wn * 64 + jn * 16 + l15) * 64 + l4 * 8];
        bhalf8 bk1 = *(const bhalf8*)&Ks[(wn * 64 + jn * 16 + l15) * 64 + 32 + l4 * 8];
        f32x4 sacc = {};
        sacc = __builtin_amdgcn_mfma_f32_16x16x32_bf16(aq0, bk0, sacc, 0, 0, 0);
        sacc = __builtin_amdgcn_mfma_f32_16x16x32_bf16(aq1, bk1, sacc, 0, 0, 0);
        int bit = jn * 16 + l15;
#pragma unroll
        for (int r = 0; r < 4; ++r)
          pv[i][jn][r] = ((mword[r] >> bit) & 1ull)
                             ? __expf(sacc[r]) * rinv[lrow0 + i * 16 + r] : 0.f;
      }
    }
    __syncthreads();   // all waves done reading Ks before Ps overwrite
#pragma unroll
    for (int i = 0; i < 4; ++i)
#pragma unroll
      for (int jn = 0; jn < 4; ++jn)
#pragma unroll
        for (int r = 0; r < 4; ++r)
          Ps[(lrow0 + i * 16 + r) * 128 + wn * 64 + jn * 16 + l15] = (bhalf)pv[i][jn][r];
    __syncthreads();
    // coalesced attention write (fp32, float4)
    {
      float* dst = att + ((long)bh * S_ + qt * 128) * S_ + kt * 128;
#pragma unroll
      for (int rep = 0; rep < 16; ++rep) {
        int idx = rep * 256 + tid;      // 4096 float4 groups
        int row = idx >> 5;
        int cg = (idx & 31) * 4;
        const bhalf* p4 = &Ps[row * 128 + cg];
        float4 o;
        o.x = (float)p4[0]; o.y = (float)p4[1]; o.z = (float)p4[2]; o.w = (float)p4[3];
        *(float4*)(dst + (long)row * S_ + cg) = o;
      }
    }
    // PV: oacc += P(128x128) * V(128x64)
#pragma unroll
    for (int t = 0; t < 4; ++t) {
      bhalf8 ap[2], bv[4];
#pragma unroll
      for (int mi = 0; mi < 2; ++mi)
        ap[mi] = *(const bhalf8*)&Ps[(prow + mi * 16 + l15) * 128 + t * 32 + l4 * 8];
#pragma unroll
      for (int nj = 0; nj < 4; ++nj)
        bv[nj] = *(const bhalf8*)&Vs[(nj * 16 + l15) * 128 + t * 32 + l4 * 8];
#pragma unroll
      for (int mi = 0; mi < 2; ++mi)
#pragma unroll
        for (int nj = 0; nj < 4; ++nj)
          oacc[mi][nj] = __builtin_amdgcn_mfma_f32_16x16x32_bf16(ap[mi], bv[nj], oacc[mi][nj], 0, 0, 0);
    }
    __syncthreads();
  }
  // write context (bf16) into [B*S, DM] assembly buffer
#pragma unroll
  for (int mi = 0; mi < 2; ++mi)
#pragma unroll
    for (int nj = 0; nj < 4; ++nj)
#pragma unroll
      for (int r = 0; r < 4; ++r) {
        int lq = prow + mi * 16 + l4 * 4 + r;
        int d = nj * 16 + l15;
        int gq = qt * 128 + lq;
        ctx[((long)(b * S_ + gq)) * DM_ + (bh & 15) * DK_ + d] = (bhalf)oacc[mi][nj][r];
      }
}

extern "C" void kernel_launch(void* const* d_in, const int* in_sizes, int n_in,
                              void* d_out, int out_size, void* d_ws, size_t ws_size,
                              hipStream_t stream) {
  const float* q  = (const float*)d_in[0];
  const float* k  = (const float*)d_in[1];
  const float* v  = (const float*)d_in[2];
  const int*   mask = (const int*)d_in[3];
  const float* Wq = (const float*)d_in[4];
  const float* Wk = (const float*)d_in[5];
  const float* Wv = (const float*)d_in[6];
  const float* Wo = (const float*)d_in[7];
  const float* bo = (const float*)d_in[8];
  float* out = (float*)d_out;
  float* att = out + (size_t)B_ * S_ * DM_;

  char* ws = (char*)d_ws;
  bhalf* qb  = (bhalf*)(ws);
  bhalf* kb  = (bhalf*)(ws + (16ull << 20));
  bhalf* vb  = (bhalf*)(ws + (32ull << 20));
  bhalf* Wqb = (bhalf*)(ws + (48ull << 20));
  bhalf* Wkb = (bhalf*)(ws + (50ull << 20));
  bhalf* Wvb = (bhalf*)(ws + (52ull << 20));
  bhalf* Wob = (bhalf*)(ws + (54ull << 20));
  bhalf* Qh  = (bhalf*)(ws + (56ull << 20));
  bhalf* Kh  = (bhalf*)(ws + (72ull << 20));
  bhalf* Vt  = (bhalf*)(ws + (88ull << 20));
  bhalf* ctx = (bhalf*)(ws + (104ull << 20));
  unsigned long long* mb = (unsigned long long*)(ws + (120ull << 20));

  const int NQKV = B_ * S_ * DM_;    // 8388608
  const int NW = DM_ * DM_;          // 1048576
  cvt_kernel<<<NQKV / 2048, 256, 0, stream>>>(q, qb, NQKV);
  cvt_kernel<<<NQKV / 2048, 256, 0, stream>>>(k, kb, NQKV);
  cvt_kernel<<<NQKV / 2048, 256, 0, stream>>>(v, vb, NQKV);
  cvt_kernel<<<NW / 2048, 256, 0, stream>>>(Wq, Wqb, NW);
  cvt_kernel<<<NW / 2048, 256, 0, stream>>>(Wk, Wkb, NW);
  cvt_kernel<<<NW / 2048, 256, 0, stream>>>(Wv, Wvb, NW);
  cvt_kernel<<<NW / 2048, 256, 0, stream>>>(Wo, Wob, NW);
  maskpack_kernel<<<(B_ * S_ * S_) / 256, 256, 0, stream>>>(mask, mb);

  dim3 gg(DM_ / 128, (B_ * S_) / 128);   // (8, 64)
  gemm_bt<0><<<gg, 256, 0, stream>>>(qb, Wqb, Qh, nullptr, nullptr, 0.125f);
  gemm_bt<0><<<gg, 256, 0, stream>>>(kb, Wkb, Kh, nullptr, nullptr, 1.0f);
  gemm_bt<1><<<gg, 256, 0, stream>>>(vb, Wvb, Vt, nullptr, nullptr, 1.0f);

  attn_kernel<<<B_ * H_ * (S_ / 128), 256, 0, stream>>>(Qh, Kh, Vt, mb, ctx, att);

  gemm_bt<2><<<gg, 256, 0, stream>>>(ctx, Wob, nullptr, out, bo, 1.0f);
}